// Round 5
// baseline (430.367 us; speedup 1.0000x reference)
//
#include <hip/hip_runtime.h>
#include <hip/hip_fp16.h>

#define HID 50
#define LAT 16
#define NW  4          // waves per block (independent after one-time dt staging)
#define BLK (NW * 64)
#define MPW 16         // batch elements per wave (one MFMA M-tile)

typedef __attribute__((ext_vector_type(8))) _Float16 half8v;  // 8 f16 = 4 VGPRs
typedef __attribute__((ext_vector_type(4))) float f32x4;
typedef __attribute__((ext_vector_type(2))) float f32x2;
typedef __attribute__((ext_vector_type(4))) unsigned uint4v;

#define MFMAH(a, b, c) __builtin_amdgcn_mfma_f32_16x16x32_f16(a, b, c, 0, 0, 0)

// ---- explicit VOP3P packed-f32 (R5): clang scalarizes generic <2 x float>
// IR on gfx950 (R4 counter arithmetic: measured VALU ~810 instr/M-tile-step
// vs ~350 expected packed); these asm wrappers pin the packed forms.
// Non-volatile, no side effects: scheduler may still interleave freely.
__device__ __forceinline__ f32x2 pk_mul(f32x2 a, f32x2 b) {
    f32x2 d;
    asm("v_pk_mul_f32 %0, %1, %2" : "=v"(d) : "v"(a), "v"(b));
    return d;
}
__device__ __forceinline__ f32x2 pk_fma(f32x2 a, f32x2 b, f32x2 c) {
    f32x2 d;
    asm("v_pk_fma_f32 %0, %1, %2, %3" : "=v"(d) : "v"(a), "v"(b), "v"(c));
    return d;
}

// pack two fp32 -> dword of 2 f16 (v_cvt_pkrtz_f16_f32, 1 instr)
__device__ __forceinline__ unsigned pkhf(float lo, float hi) {
    __half2 h = __float22half2_rn(float2{lo, hi});
    unsigned r;
    __builtin_memcpy(&r, &h, 4);
    return r;
}

// kappa-label -> hidden-unit map (R15 repack).  Tiles 0-2 hold real units
// 0..47; tile 3 holds units 48,49 at m=0,1 (q=0), the bias/sat slot at
// kappa==38 (m=2, q=0), everything else dead.
__device__ __forceinline__ int unitmap(int k, bool& dead, bool& sat) {
    dead = false; sat = false;
    int u = k;
    if (k == 36)                          u = 48;
    else if (k == 37)                     u = 49;
    else if (k == 38)                     sat = true;
    else if (k == 39)                     dead = true;
    else if (k >= 44 && k < 48)           dead = true;
    else if ((k >= 48 && k < 52) || (k >= 56 && k < 60)) u = k - 12;
    else if (k >= 52 && k < 56)           dead = true;
    else if (k >= 60)                     dead = true;
    return u;   // k<36 (not 36-39) and 40-43: identity
}

// ---- A-frag builders (weights as f16 MFMA A-operand; one-time setup) ----
__device__ __forceinline__ half8v afrag1(const float* __restrict__ W, const float* __restrict__ bias,
                                         int Kreal, int ti, int q, int m, float scale) {
    int kap = 32 * (ti >> 1) + 8 * (m >> 2) + 4 * (ti & 1) + (m & 3);
    bool dead, sat;
    int u = unitmap(kap, dead, sat);
    float e[8];
#pragma unroll
    for (int j = 0; j < 8; j++) {
        float f = 0.0f;
        if (!dead && !sat) {
            if (j < 4) {
                int row = 4 * q + j;
                if (row < Kreal) f = W[row * HID + u] * scale;
            } else if (j == 4 && q == 0) f = bias[u] * scale;
        }
        e[j] = f;
    }
    uint4v d;
#pragma unroll
    for (int p = 0; p < 4; p++) d[p] = pkhf(e[2 * p], e[2 * p + 1]);
    return __builtin_bit_cast(half8v, d);
}

__device__ __forceinline__ half8v afrag2(const float* __restrict__ W2, const float* __restrict__ b2,
                                         int N2, int chunk, int q, int m) {
    float e[8];
#pragma unroll
    for (int j = 0; j < 8; j++) {
        int kap = 32 * chunk + 8 * q + j;
        bool dead, sat;
        int u = unitmap(kap, dead, sat);
        float f = 0.0f;
        if (m < N2) {
            if (sat)       f = b2[m];
            else if (!dead) f = W2[u * N2 + m];
        }
        e[j] = f;
    }
    uint4v d;
#pragma unroll
    for (int p = 0; p < 4; p++) d[p] = pkhf(e[2 * p], e[2 * p + 1]);
    return __builtin_bit_cast(half8v, d);
}

__global__ void __attribute__((amdgpu_flat_work_group_size(BLK, BLK), amdgpu_waves_per_eu(4, 4)))
node_kernel(const float* __restrict__ x0, const float* __restrict__ tt,
            const float* __restrict__ We1, const float* __restrict__ be1,
            const float* __restrict__ We2, const float* __restrict__ be2,
            const float* __restrict__ Wo1, const float* __restrict__ bo1,
            const float* __restrict__ Wo2, const float* __restrict__ bo2,
            const float* __restrict__ Wd1, const float* __restrict__ bd1,
            const float* __restrict__ Wd2, const float* __restrict__ bd2,
            float* __restrict__ out, int B, int T) {
    __shared__ float sdt[128];   // dt table (lgkm-side; loop stays vmcnt-free)
    {
        int idx = threadIdx.x;
        if (idx < T - 1) sdt[idx] = tt[idx + 1] - tt[idx];
    }
    __syncthreads();   // one-time; waves independent afterwards

    const int lane = threadIdx.x & 63;
    const int q    = lane >> 4;          // quad
    const int c    = lane & 15;          // batch col in B/CD frags; row m in A frags
    const int wid  = threadIdx.x >> 6;
    const int wbase = blockIdx.x * (NW * MPW) + wid * MPW;

    const f32x4 zero4 = {0.0f, 0.0f, 0.0f, 0.0f};
    const unsigned biasdw = (q == 0) ? 0x3C00u : 0u;

    // Trans-free tanh (R3 numerics, R5 lowering): odd poly x*P(x^2), deg-9,
    // Chebyshev fit on |x|<=2, clamp via v_med3.  Coeff pairs live in VGPRs
    // for the asm pk ops (hoisted out of the loop; bit-identical results).
    const f32x2 tc0 = { 0.998805f,  0.998805f};
    const f32x2 tc1 = {-0.317916f, -0.317916f};
    const f32x2 tc2 = { 0.097206f,  0.097206f};
    const f32x2 tc3 = {-0.018404f, -0.018404f};
    const f32x2 tc4 = { 0.001476f,  0.001476f};

    // 9 instrs/pair guaranteed: 2 med3 + 1 pk_mul + 4 pk_fma + 1 pk_mul + 1 cvt_pk
    auto tanh2 = [&](float a, float b) -> unsigned {
        f32x2 x;
        x[0] = __builtin_amdgcn_fmed3f(a, -2.0f, 2.0f);
        x[1] = __builtin_amdgcn_fmed3f(b, -2.0f, 2.0f);
        f32x2 s = pk_mul(x, x);
        f32x2 p = pk_fma(s, tc4, tc3);
        p = pk_fma(p, s, tc2);
        p = pk_fma(p, s, tc1);
        p = pk_fma(p, s, tc0);
        p = pk_mul(p, x);
        return pkhf(p[0], p[1]);
    };

    // ---- persistent weight A-frags (f16; whole kernel) ----
    half8v A1o[4], A1d[4], A2o[2], A2d[2];
#pragma unroll
    for (int ti = 0; ti < 4; ti++) {
        A1o[ti] = afrag1(Wo1, bo1, LAT, ti, q, c, 1.0f);
        A1d[ti] = afrag1(Wd1, bd1, LAT, ti, q, c, 1.0f);
    }
#pragma unroll
    for (int ch = 0; ch < 2; ch++) {
        A2o[ch] = afrag2(Wo2, bo2, LAT, ch, q, c);
        A2d[ch] = afrag2(Wd2, bd2, 1, ch, q, c);
    }

    // ---- Encoder (transient f16 frags), relu in f32 then pack ----
    f32x4 z;
    {
        uint4v bx = {0u, 0u, 0u, 0u};
        if (q == 0) {  // x at k=0,1; bias 1.0 at k=4
            bx[0] = pkhf(x0[2 * (wbase + c)], x0[2 * (wbase + c) + 1]);
            bx[2] = 0x3C00u;
        }
        half8v Bx = __builtin_bit_cast(half8v, bx);
        f32x4 h0 = MFMAH(afrag1(We1, be1, 2, 0, q, c, 1.0f), Bx, zero4);
        f32x4 h1 = MFMAH(afrag1(We1, be1, 2, 1, q, c, 1.0f), Bx, zero4);
        f32x4 h2 = MFMAH(afrag1(We1, be1, 2, 2, q, c, 1.0f), Bx, zero4);
        f32x4 h3 = MFMAH(afrag1(We1, be1, 2, 3, q, c, 1.0f), Bx, zero4);
        uint4v d0 = {pkhf(fmaxf(h0[0], 0.f), fmaxf(h0[1], 0.f)), pkhf(fmaxf(h0[2], 0.f), fmaxf(h0[3], 0.f)),
                     pkhf(fmaxf(h1[0], 0.f), fmaxf(h1[1], 0.f)), pkhf(fmaxf(h1[2], 0.f), fmaxf(h1[3], 0.f))};
        uint4v d1 = {pkhf(fmaxf(h2[0], 0.f), fmaxf(h2[1], 0.f)), pkhf(fmaxf(h2[2], 0.f), fmaxf(h2[3], 0.f)),
                     pkhf(fmaxf(h3[0], 0.f), fmaxf(h3[1], 0.f)), biasdw};
        z = MFMAH(afrag2(We2, be2, 16, 1, q, c), __builtin_bit_cast(half8v, d1),
            MFMAH(afrag2(We2, be2, 16, 0, q, c), __builtin_bit_cast(half8v, d0), zero4));
    }

    // z (CD layout: lat 4q+r, batch c) -> GEMM1 B-frag: k(j<4)=lat 4q+j, bias at k=4
    auto mkzfrag = [&](f32x4 zz) -> half8v {
        uint4v d = {pkhf(zz[0], zz[1]), pkhf(zz[2], zz[3]), biasdw, 0u};
        return __builtin_bit_cast(half8v, d);
    };

    // ODE func: 6 MFMA + packed poly tanh on 7 value-pairs (14 values).
    auto odef = [&](half8v zf) -> f32x4 {
        f32x4 h0 = MFMAH(A1o[0], zf, zero4);
        f32x4 h1 = MFMAH(A1o[1], zf, zero4);
        f32x4 h2 = MFMAH(A1o[2], zf, zero4);
        f32x4 h3 = MFMAH(A1o[3], zf, zero4);
        uint4v d0 = {tanh2(h0[0], h0[1]), tanh2(h0[2], h0[3]),
                     tanh2(h1[0], h1[1]), tanh2(h1[2], h1[3])};
        uint4v d1 = {tanh2(h2[0], h2[1]), tanh2(h2[2], h2[3]),
                     tanh2(h3[0], h3[1]), biasdw};
        return MFMAH(A2o[1], __builtin_bit_cast(half8v, d1),
               MFMAH(A2o[0], __builtin_bit_cast(half8v, d0), zero4));
    };

    // decoder: relu in f32 (full-rate), pack pairs; y[c] in reg0 of q==0 lanes
    auto decode = [&](half8v zf) -> f32x4 {
        f32x4 h0 = MFMAH(A1d[0], zf, zero4);
        f32x4 h1 = MFMAH(A1d[1], zf, zero4);
        f32x4 h2 = MFMAH(A1d[2], zf, zero4);
        f32x4 h3 = MFMAH(A1d[3], zf, zero4);
        uint4v d0 = {pkhf(fmaxf(h0[0], 0.f), fmaxf(h0[1], 0.f)), pkhf(fmaxf(h0[2], 0.f), fmaxf(h0[3], 0.f)),
                     pkhf(fmaxf(h1[0], 0.f), fmaxf(h1[1], 0.f)), pkhf(fmaxf(h1[2], 0.f), fmaxf(h1[3], 0.f))};
        uint4v d1 = {pkhf(fmaxf(h2[0], 0.f), fmaxf(h2[1], 0.f)), pkhf(fmaxf(h2[2], 0.f), fmaxf(h2[3], 0.f)),
                     pkhf(fmaxf(h3[0], 0.f), fmaxf(h3[1], 0.f)), biasdw};
        return MFMAH(A2d[1], __builtin_bit_cast(half8v, d1),
               MFMAH(A2d[0], __builtin_bit_cast(half8v, d0), zero4));
    };

    // ---- main time loop: register dataflow; only VMEM op is the out store.
    // dt prefetch (R5): issue sdt[s+1] ds_read at iteration top, consume next
    // iteration -- takes the ~120cy LDS latency off the serial chain.
    // sdt[T-1] is read-but-unused garbage (within bounds; safe).
    float dt = sdt[0];
    for (int s = 0;; s++) {
        half8v zf = mkzfrag(z);
        f32x4 y = decode(zf);
        if (lane < 16) out[(size_t)s * B + wbase + c] = y[0];

        if (s == T - 1) break;
        float dtn = sdt[s + 1];

        f32x4 k = odef(zf);                          // k1 (shares zf with decode)
        f32x4 ksum = k;
        f32x4 ztmp = z + (0.5f * dt) * k;
        k = odef(mkzfrag(ztmp));                     // k2
        ksum += 2.0f * k;
        ztmp = z + (0.5f * dt) * k;
        k = odef(mkzfrag(ztmp));                     // k3
        ksum += 2.0f * k;
        ztmp = z + dt * k;
        k = odef(mkzfrag(ztmp));                     // k4
        z = z + (dt * (1.0f / 6.0f)) * (ksum + k);
        dt = dtn;
    }
}

extern "C" void kernel_launch(void* const* d_in, const int* in_sizes, int n_in,
                              void* d_out, int out_size, void* d_ws, size_t ws_size,
                              hipStream_t stream) {
    const float* x0  = (const float*)d_in[0];
    const float* t   = (const float*)d_in[1];
    const float* We1 = (const float*)d_in[2];
    const float* be1 = (const float*)d_in[3];
    const float* We2 = (const float*)d_in[4];
    const float* be2 = (const float*)d_in[5];
    const float* Wo1 = (const float*)d_in[6];
    const float* bo1 = (const float*)d_in[7];
    const float* Wo2 = (const float*)d_in[8];
    const float* bo2 = (const float*)d_in[9];
    const float* Wd1 = (const float*)d_in[10];
    const float* bd1 = (const float*)d_in[11];
    const float* Wd2 = (const float*)d_in[12];
    const float* bd2 = (const float*)d_in[13];
    float* out = (float*)d_out;

    int B = in_sizes[0] / 2;   // 65536
    int T = in_sizes[1];       // 100

    dim3 block(BLK);
    dim3 grid(B / (NW * MPW)); // 1024 blocks, 4 waves each
    hipLaunchKernelGGL(node_kernel, grid, block, 0, stream,
                       x0, t, We1, be1, We2, be2, Wo1, bo1, Wo2, bo2,
                       Wd1, bd1, Wd2, bd2, out, B, T);
}